// Round 13
// baseline (116.408 us; speedup 1.0000x reference)
//
#include <hip/hip_runtime.h>
#include <math.h>

typedef __attribute__((ext_vector_type(8))) short bf16x8;   // 8 bf16 (4 VGPRs)
typedef __attribute__((ext_vector_type(4))) float f32x4;    // MFMA acc

#define SQRT3F     1.7320508075688772f
#define SCALE_T    0.17677669529663687f    // 1/sqrt(32)
#define SCALE_M1   0.025515518153991442f   // C_SCALAR/sqrt(32)
#define SCALE_M2   0.014731391274719739f   // C_SCALAR*inv_sqrt3/sqrt(32)
#define SCALE_M34  0.036084391824351615f   // C_SCALAR/4

#define FSTR 40    // feature row stride (shorts): 80 B
#define ASTR 72    // agg row stride (shorts): 144 B

__device__ __forceinline__ ushort f2bf(float f) {
    union { float f; unsigned u; } v; v.f = f;
    unsigned u = v.u;
    return (ushort)((u + 0x7FFFu + ((u >> 16) & 1u)) >> 16);
}
__device__ __forceinline__ float bf2f(ushort h) {
    union { unsigned u; float f; } v; v.u = ((unsigned)h) << 16;
    return v.f;
}
__device__ __forceinline__ f32x4 mfma(bf16x8 a, bf16x8 b, f32x4 c) {
    return __builtin_amdgcn_mfma_f32_16x16x32_bf16(a, b, c, 0, 0, 0);
}
// stage-1 D-tile -> agg[nloc][u0..u0+3], bf16 packed
__device__ __forceinline__ void storeAgg(ushort* AG, f32x4 t, int u0, int n) {
    uint2 u;
    u.x = f2bf(t[0]) | ((unsigned)f2bf(t[1]) << 16);
    u.y = f2bf(t[2]) | ((unsigned)f2bf(t[3]) << 16);
    *(uint2*)&AG[n*ASTR + u0] = u;
}
// residual + relu RMW of 4 consecutive nodes at channel c (packed uint2)
__device__ __forceinline__ void rmw4(ushort* F, int c, int n0, f32x4 h) {
    uint2* p = (uint2*)&F[c*FSTR + n0];
    uint2 o = *p;
    float f0 = bf2f((ushort)(o.x      )) + fmaxf(h[0], 0.f);
    float f1 = bf2f((ushort)(o.x >> 16)) + fmaxf(h[1], 0.f);
    float f2 = bf2f((ushort)(o.y      )) + fmaxf(h[2], 0.f);
    float f3 = bf2f((ushort)(o.y >> 16)) + fmaxf(h[3], 0.f);
    uint2 w;
    w.x = f2bf(f0) | ((unsigned)f2bf(f1) << 16);
    w.y = f2bf(f2) | ((unsigned)f2bf(f3) << 16);
    *p = w;
}

// ---------------------------------------------------------------------------
// Prep (tiny, one-shot): Tbf (100x32 bf16) and Mbf (3 layers x 48 rows x 64,
// transposed folded update matrices, K-pad cols 48..63 = 0).
// ---------------------------------------------------------------------------
__global__ void prep_kernel(const float* __restrict__ emb,
                            const float* __restrict__ W_s2n,
                            const float* __restrict__ W1, const float* __restrict__ W2,
                            const float* __restrict__ W3, const float* __restrict__ W4,
                            const float* __restrict__ Ws, const float* __restrict__ Wv,
                            ushort* __restrict__ Tbf, ushort* __restrict__ Mbf)
{
    int idx = blockIdx.x * blockDim.x + threadIdx.x;
    if (idx < 3200) {
        int r = idx >> 5, c = idx & 31;
        float acc = 0.f;
        for (int k = 0; k < 32; ++k) acc += emb[r*32 + k] * W_s2n[k*32 + c];
        Tbf[idx] = f2bf(acc * SCALE_T);
        return;
    }
    idx -= 3200;
    if (idx < 3*48*64) {
        int lyr = idx / 3072, rem = idx % 3072;
        int row = rem >> 6, u = rem & 63;
        float val = 0.f;
        if (row < 32) {
            int w = row;
            if (u < 32) {
                float a = 0.f;
                for (int k = 0; k < 32; ++k)
                    a += W1[lyr*1024 + u*32 + k] * Ws[lyr*1024 + k*32 + w];
                val = a * SCALE_M1;
            } else if (u < 48) {
                int uu = u - 32; float a = 0.f;
                for (int k = 0; k < 32; ++k)
                    a += W4[lyr*512 + uu*32 + k] * Ws[lyr*1024 + k*32 + w];
                val = a * SCALE_M2;
            }
        } else {
            int w = row - 32;
            if (u < 32) {
                float a = 0.f;
                for (int k = 0; k < 16; ++k)
                    a += W2[lyr*512 + u*16 + k] * Wv[lyr*256 + k*16 + w];
                val = a * SCALE_M34;
            } else if (u < 48) {
                int uu = u - 32; float a = 0.f;
                for (int k = 0; k < 16; ++k)
                    a += W3[lyr*256 + uu*16 + k] * Wv[lyr*256 + k*16 + w];
                val = a * SCALE_M34;
            }
        }
        Mbf[lyr*3072 + row*64 + u] = f2bf(val);
    }
}

// ---------------------------------------------------------------------------
// Fused GNN + MLP. TWO waves per graph (node-tiles 0..15 / 16..31), 2 graphs
// per 256-thread block -> 1024 blocks = 16 waves/CU (2x round-12's 8: the
// one-wave-per-graph layout was grid-capped at 25% occupancy, latency-bound
// on the MFMA->LDS->MFMA chain). feat shared per graph; agg wave-private;
// 2 barriers/layer (pre-update fragment loads || RMW).
// Stage 1: agg[n][u] = feat x Adj^T (m89 scheme). Stage 2 flipped:
// mfma(agg,M) -> D rows = nodes -> packed uint2 residual RMW.
// ---------------------------------------------------------------------------
__global__ __launch_bounds__(256, 4)
void gnn_kernel(const float* __restrict__ pos, const int* __restrict__ z,
                const ushort* __restrict__ Tbf, const ushort* __restrict__ Mbf,
                const float* __restrict__ Wr1, const float* __restrict__ br1,
                const float* __restrict__ Wr2, const float* __restrict__ br2,
                float* __restrict__ out, int B)
{
    __shared__ __align__(16) char smem[22656];
    ushort* featA = (ushort*)smem;                    // 2*80*40*2 = 12800 B
    ushort* aggA  = (ushort*)(smem + 12800);          // 4*16*72*2 =  9216 B
    float*  hgl   = (float*)(smem + 22016);           // 2*80*4    =   640 B
    float*  h1    = (float*)aggA;                     // alias (post-layers)

    const int tid = threadIdx.x;
    const int wv = tid >> 6, l = tid & 63;
    const int gw = wv >> 1;            // graph within block (0..1)
    const int mt = wv & 1;             // node-tile of this wave (0..1)
    const int g  = blockIdx.x*2 + gw;
    ushort* F  = featA + gw*80*FSTR;   // per-graph (shared by 2 waves)
    ushort* AG = aggA  + wv*16*ASTR;   // per-wave

    // zero agg (incl. K-pad cols 48..63)
    for (int i = l; i < 16*(ASTR/2); i += 64) ((uint*)AG)[i] = 0;
    // per-graph cooperative init (128 threads per graph)
    {
        const int t2 = tid & 127;
        // zero v rows
        for (int i = t2; i < 48*(FSTR/2); i += 128) ((uint*)(F + 32*FSTR))[i] = 0;
        // s init: F[c][n] = Tbf[z[n]][c], 8 channels per thread
        int n = t2 & 31, h = t2 >> 5;           // h = 0..3
        int zg = z[g*32 + n];
        uint4 t0 = *(const uint4*)(Tbf + zg*32 + h*8);
        unsigned ua[4] = {t0.x, t0.y, t0.z, t0.w};
        #pragma unroll
        for (int q = 0; q < 4; ++q) {
            F[(h*8 + 2*q    )*FSTR + n] = (ushort)ua[q];
            F[(h*8 + 2*q + 1)*FSTR + n] = (ushort)(ua[q] >> 16);
        }
    }

    // adjacency fragments for THIS wave's node-tile (layer-invariant, 16 VGPRs)
    const int ln = l & 15, kq = l >> 4;
    bf16x8 adjf[4];
    {
        const int k0 = kq*8;
        int ng = g*32 + mt*16 + ln;
        float px = pos[3*ng], py = pos[3*ng+1], pz = pos[3*ng+2];
        union { bf16x8 v; ushort s[8]; } o[4];
        #pragma unroll
        for (int jj = 0; jj < 8; ++jj) {
            int j = g*32 + k0 + jj;
            float dx = __fsub_rn(px, pos[3*j]);
            float dy = __fsub_rn(py, pos[3*j+1]);
            float dz = __fsub_rn(pz, pos[3*j+2]);
            float d2 = __fadd_rn(__fadd_rn(__fmul_rn(dx,dx), __fmul_rn(dy,dy)),
                                 __fmul_rn(dz,dz));
            bool on = (d2 <= 25.0f) && (d2 > 0.0f);
            float rinv = on ? rsqrtf(d2) * SQRT3F : 0.f;
            o[0].s[jj] = on ? (ushort)0x3F80 : (ushort)0;   // bf16(1.0)
            o[1].s[jj] = f2bf(dx * rinv);
            o[2].s[jj] = f2bf(dy * rinv);
            o[3].s[jj] = f2bf(dz * rinv);
        }
        #pragma unroll
        for (int w = 0; w < 4; ++w) adjf[w] = o[w].v;
    }
    __syncthreads();   // init complete

    const f32x4 z4 = {0.f, 0.f, 0.f, 0.f};

    for (int lay = 0; lay < 3; ++lay) {
        const ushort* Mg = Mbf + lay*3072;
        // pre-update feature fragments (channels row ln, node cols kq*8..)
        bf16x8 fs0 = *(const bf16x8*)&F[(     ln)*FSTR + kq*8];
        bf16x8 fs1 = *(const bf16x8*)&F[(16 + ln)*FSTR + kq*8];
        bf16x8 fv0 = *(const bf16x8*)&F[(32 + ln)*FSTR + kq*8];
        bf16x8 fv1 = *(const bf16x8*)&F[(48 + ln)*FSTR + kq*8];
        bf16x8 fv2 = *(const bf16x8*)&F[(64 + ln)*FSTR + kq*8];
        // M fragments (global, L1-hot)
        bf16x8 bmS0[2], bmS1[2], bmV[2];
        #pragma unroll
        for (int kc = 0; kc < 2; ++kc) {
            bmS0[kc] = *(const bf16x8*)&Mg[(     ln)*64 + kc*32 + kq*8];
            bmS1[kc] = *(const bf16x8*)&Mg[(16 + ln)*64 + kc*32 + kq*8];
            bmV [kc] = *(const bf16x8*)&Mg[(32 + ln)*64 + kc*32 + kq*8];
        }
        __syncthreads();   // all waves have their pre-update fragments

        // ---- scalar path: agg = [A0 (u<32) | a3 (u 32..47)] for my nodes
        {
            f32x4 t;
            t = mfma(fs0, adjf[0], z4);
            storeAgg(AG, t,      kq*4, ln);
            t = mfma(fs1, adjf[0], z4);
            storeAgg(AG, t, 16 + kq*4, ln);
            t = mfma(fv2, adjf[3], z4);
            t = mfma(fv1, adjf[2], t);
            t = mfma(fv0, adjf[1], t);
            storeAgg(AG, t, 32 + kq*4, ln);
        }
        f32x4 hs[2] = {z4, z4};   // [w-tile]
        #pragma unroll
        for (int kc = 0; kc < 2; ++kc) {
            bf16x8 ag = *(const bf16x8*)&AG[ln*ASTR + kc*32 + kq*8];
            hs[0] = mfma(ag, bmS0[kc], hs[0]);
            hs[1] = mfma(ag, bmS1[kc], hs[1]);
        }
        #pragma unroll
        for (int wt = 0; wt < 2; ++wt)
            rmw4(F, wt*16 + ln, mt*16 + kq*4, hs[wt]);

        // ---- vector path, one spatial component at a time (reuses AG)
        #pragma unroll
        for (int i = 0; i < 3; ++i) {
            bf16x8 fvi = (i == 0) ? fv0 : (i == 1) ? fv1 : fv2;
            {
                f32x4 t;
                t = mfma(fs0, adjf[1+i], z4);
                storeAgg(AG, t,      kq*4, ln);
                t = mfma(fs1, adjf[1+i], z4);
                storeAgg(AG, t, 16 + kq*4, ln);
                t = mfma(fvi, adjf[0], z4);
                storeAgg(AG, t, 32 + kq*4, ln);
            }
            f32x4 hv = z4;
            #pragma unroll
            for (int kc = 0; kc < 2; ++kc) {
                bf16x8 ag = *(const bf16x8*)&AG[ln*ASTR + kc*32 + kq*8];
                hv = mfma(ag, bmV[kc], hv);
            }
            rmw4(F, 32 + i*16 + ln, mt*16 + kq*4, hv);
        }
        __syncthreads();   // layer updates visible to partner wave
    }

    // pool: 2 graphs x 80 features over 32 nodes
    if (tid < 160) {
        int pg = tid / 80, f = tid - pg*80;
        const ushort* row;
        ushort* Fp = featA + pg*80*FSTR;
        if (f < 32) row = &Fp[f*FSTR];
        else { int c = f - 32, w = c/3, i = c - 3*w; row = &Fp[(32 + i*16 + w)*FSTR]; }
        const uint* r32 = (const uint*)row;
        float acc = 0.f;
        #pragma unroll
        for (int q = 0; q < 16; ++q) {
            uint u = r32[q];
            acc += bf2f((ushort)u) + bf2f((ushort)(u >> 16));
        }
        hgl[pg*80 + f] = acc;
    }
    __syncthreads();   // agg region dead; hgl complete

    // --- fused MLP head (block = its 2 graphs) ---
    {
        const int w = tid;
        float acc0 = br1[w];
        float acc1 = acc0;
        #pragma unroll 4
        for (int f = 0; f < 80; ++f) {
            float wvv = Wr1[f*256 + w];
            acc0 = fmaf(hgl[0*80 + f], wvv, acc0);
            acc1 = fmaf(hgl[1*80 + f], wvv, acc1);
        }
        h1[0*256 + w] = fmaxf(acc0, 0.f);
        h1[1*256 + w] = fmaxf(acc1, 0.f);
    }
    __syncthreads();
    {
        const int pg = tid >> 7, w2 = tid & 127;
        const float4* h1v = (const float4*)(h1 + pg*256);   // 64 float4
        float s = 0.f;
        #pragma unroll 4
        for (int k4 = 0; k4 < 64; ++k4) {
            float4 hA = h1v[k4];
            int k = k4 * 4;
            float m0 = Wr2[(size_t)(k+0)*128 + w2];
            float m1 = Wr2[(size_t)(k+1)*128 + w2];
            float m2 = Wr2[(size_t)(k+2)*128 + w2];
            float m3 = Wr2[(size_t)(k+3)*128 + w2];
            s = fmaf(hA.x,m0, fmaf(hA.y,m1, fmaf(hA.z,m2, fmaf(hA.w,m3, s))));
        }
        out[(size_t)(blockIdx.x*2 + pg)*128 + w2] = s + br2[w2];
    }
}

// ---------------------------------------------------------------------------
extern "C" void kernel_launch(void* const* d_in, const int* in_sizes, int n_in,
                              void* d_out, int out_size, void* d_ws, size_t ws_size,
                              hipStream_t stream)
{
    const float* pos   = (const float*)d_in[0];
    const int*   z     = (const int*)d_in[1];
    const float* emb   = (const float*)d_in[5];
    const float* W_s2n = (const float*)d_in[6];
    const float* W1    = (const float*)d_in[7];
    const float* W2    = (const float*)d_in[8];
    const float* W3    = (const float*)d_in[9];
    const float* W4    = (const float*)d_in[10];
    const float* Ws    = (const float*)d_in[11];
    const float* Wv    = (const float*)d_in[12];
    const float* Wr1   = (const float*)d_in[13];
    const float* br1   = (const float*)d_in[14];
    const float* Wr2   = (const float*)d_in[15];
    const float* br2   = (const float*)d_in[16];
    float* out = (float*)d_out;

    const int B = out_size / 128;      // graphs (2048)

    // workspace: Tbf (3200 shorts) | Mbf (9216 shorts)
    char* p = (char*)d_ws;
    ushort* Tbf = (ushort*)p;  p += 6400;
    ushort* Mbf = (ushort*)p;  p += 18432;

    const int prep_total = 3200 + 3*48*64;
    prep_kernel<<<(prep_total + 255) / 256, 256, 0, stream>>>(
        emb, W_s2n, W1, W2, W3, W4, Ws, Wv, Tbf, Mbf);

    gnn_kernel<<<B / 2, 256, 0, stream>>>(pos, z, Tbf, Mbf,
                                          Wr1, br1, Wr2, br2, out, B);
}